// Round 15
// baseline (242.742 us; speedup 1.0000x reference)
//
#include <hip/hip_runtime.h>
#include <hip/hip_bf16.h>
#include <math.h>

#define E_DIM  1024
#define H_DIM  16
#define D_DIM  64
#define T_SEQ  1024
#define B_SZ   4
#define E3     3072
#define R_RANK 4

typedef __attribute__((ext_vector_type(8))) short bf16x8;
typedef __attribute__((ext_vector_type(8))) unsigned short u16x8;
typedef __attribute__((ext_vector_type(4))) float f32x4;

static __device__ __forceinline__ ushort f2bf(float x) {
  __hip_bfloat16 h = __float2bfloat16(x);
  return *(ushort*)&h;
}
static __device__ __forceinline__ float bf2f(ushort u) {
  unsigned int v = ((unsigned int)u) << 16;
  float f;
  __builtin_memcpy(&f, &v, 4);
  return f;
}

// Raw barrier with LDS-only drain (keeps register-destined global prefetches
// in flight across the barrier).
static __device__ __forceinline__ void barrier_lgkm() {
  asm volatile("s_waitcnt lgkmcnt(0)" ::: "memory");
  __builtin_amdgcn_s_barrier();
  __builtin_amdgcn_sched_barrier(0);
}

#define GLOAD_LDS16(g, l)                                                     \
  __builtin_amdgcn_global_load_lds(                                           \
      (const __attribute__((address_space(1))) void*)(g),                     \
      (__attribute__((address_space(3))) void*)(l), 16, 0, 0)

// ---------------- fused prep: casts + 3 factorizations, one launch ----------
static __device__ __forceinline__ void fact4(
    const float* __restrict__ W, const float* __restrict__ rm,
    const float* __restrict__ sm, const float* __restrict__ r,
    const float* __restrict__ s, ushort* __restrict__ out,
    int A, int idx, long long t) {
  long long i4 = t * 4;
  int a = (int)(i4 >> 10);        // Bc = 1024 for all three
  int bcol = (int)(i4 & 1023);
  float4 wv = *(const float4*)(W + i4);
  float ra = rm[(long long)idx * A + a];
  float4 sv = *(const float4*)(sm + (long long)idx * 1024 + bcol);
  float4 acc;
  acc.x = wv.x * ra * sv.x; acc.y = wv.y * ra * sv.y;
  acc.z = wv.z * ra * sv.z; acc.w = wv.w * ra * sv.w;
#pragma unroll
  for (int k = 0; k < R_RANK; ++k) {
    float rk = r[((long long)idx * R_RANK + k) * A + a];
    float4 sk = *(const float4*)(s + ((long long)idx * R_RANK + k) * 1024 + bcol);
    acc.x += rk * sk.x; acc.y += rk * sk.y;
    acc.z += rk * sk.z; acc.w += rk * sk.w;
  }
  ushort4 o;
  o.x = f2bf(acc.x); o.y = f2bf(acc.y); o.z = f2bf(acc.z); o.w = f2bf(acc.w);
  *(ushort4*)(out + i4) = o;
}

__global__ __launch_bounds__(256) void prep_kernel(
    const float* __restrict__ input, const float* __restrict__ pos,
    const float* __restrict__ in_w, const float* __restrict__ pos_w,
    const float* __restrict__ out_w,
    const float* __restrict__ rm_i, const float* __restrict__ sm_i,
    const float* __restrict__ r_i, const float* __restrict__ s_i,
    const float* __restrict__ rm_p, const float* __restrict__ sm_p,
    const float* __restrict__ r_p, const float* __restrict__ s_p,
    const float* __restrict__ rm_o, const float* __restrict__ sm_o,
    const float* __restrict__ r_o, const float* __restrict__ s_o,
    const int* __restrict__ idxp,
    ushort* __restrict__ ibf, ushort* __restrict__ pbf,
    ushort* __restrict__ Wi, ushort* __restrict__ Wp,
    ushort* __restrict__ Wo) {
  const int idx = idxp[0];
  long long t = (long long)blockIdx.x * blockDim.x + threadIdx.x;
  if (t < 524288) {  // cast input: 8 f32 -> 8 bf16
    float4 v0 = *(const float4*)(input + t * 8);
    float4 v1 = *(const float4*)(input + t * 8 + 4);
    ushort4 o0, o1;
    o0.x = f2bf(v0.x); o0.y = f2bf(v0.y); o0.z = f2bf(v0.z); o0.w = f2bf(v0.w);
    o1.x = f2bf(v1.x); o1.y = f2bf(v1.y); o1.z = f2bf(v1.z); o1.w = f2bf(v1.w);
    *(ushort4*)(ibf + t * 8) = o0;
    *(ushort4*)(ibf + t * 8 + 4) = o1;
    return;
  }
  t -= 524288;
  if (t < 131072) {  // cast pos
    float4 v0 = *(const float4*)(pos + t * 8);
    float4 v1 = *(const float4*)(pos + t * 8 + 4);
    ushort4 o0, o1;
    o0.x = f2bf(v0.x); o0.y = f2bf(v0.y); o0.z = f2bf(v0.z); o0.w = f2bf(v0.w);
    o1.x = f2bf(v1.x); o1.y = f2bf(v1.y); o1.z = f2bf(v1.z); o1.w = f2bf(v1.w);
    *(ushort4*)(pbf + t * 8) = o0;
    *(ushort4*)(pbf + t * 8 + 4) = o1;
    return;
  }
  t -= 131072;
  if (t < 786432) { fact4(in_w, rm_i, sm_i, r_i, s_i, Wi, E3, idx, t); return; }
  t -= 786432;
  if (t < 262144) { fact4(pos_w, rm_p, sm_p, r_p, s_p, Wp, E_DIM, idx, t); return; }
  t -= 262144;
  fact4(out_w, rm_o, sm_o, r_o, s_o, Wo, E_DIM, idx, t);
}

// ---------------- bf16 MFMA GEMM body (m97-style, BK=32) --------------------
template <bool BF16OUT>
static __device__ __forceinline__ void gemm_body(
    const ushort* __restrict__ A, const ushort* __restrict__ B,
    const float* __restrict__ bias, void* __restrict__ Cv,
    int N, int K, int m0, int n0, ushort* As, ushort* Bs) {
  const int tid = threadIdx.x;
  const int l = tid & 63, w = tid >> 6;
  const int mw = (w >> 1) * 64, nw = (w & 1) * 64;
  const int fr = l & 15, fq = l >> 4;
  const int lrow = l >> 2;
  const int lk = (l & 3) * 8;

  f32x4 acc[4][4];
#pragma unroll
  for (int i = 0; i < 4; ++i)
#pragma unroll
    for (int j = 0; j < 4; ++j)
#pragma unroll
      for (int q = 0; q < 4; ++q) acc[i][j][q] = 0.f;

  for (int k0 = 0; k0 < K; k0 += 32) {
    __syncthreads();
#pragma unroll
    for (int p = 0; p < 2; ++p) {
      int row = w * 32 + p * 16;
      GLOAD_LDS16(A + (long long)(m0 + row + lrow) * K + k0 + lk,
                  As + row * 32);
      GLOAD_LDS16(B + (long long)(n0 + row + lrow) * K + k0 + lk,
                  Bs + row * 32);
    }
    __syncthreads();
    bf16x8 af[4], bfr[4];
#pragma unroll
    for (int i = 0; i < 4; ++i) {
      af[i]  = *(const bf16x8*)(As + (mw + i * 16 + fr) * 32 + fq * 8);
      bfr[i] = *(const bf16x8*)(Bs + (nw + i * 16 + fr) * 32 + fq * 8);
    }
#pragma unroll
    for (int i = 0; i < 4; ++i)
#pragma unroll
      for (int j = 0; j < 4; ++j)
        acc[i][j] = __builtin_amdgcn_mfma_f32_16x16x32_bf16(
            af[i], bfr[j], acc[i][j], 0, 0, 0);
  }
#pragma unroll
  for (int i = 0; i < 4; ++i) {
#pragma unroll
    for (int j = 0; j < 4; ++j) {
      int n = n0 + nw + j * 16 + fr;
      float bv = bias[n];
#pragma unroll
      for (int q = 0; q < 4; ++q) {
        int m = m0 + mw + i * 16 + fq * 4 + q;
        if constexpr (BF16OUT)
          ((ushort*)Cv)[(long long)m * N + n] = f2bf(acc[i][j][q] + bv);
        else
          ((float*)Cv)[(long long)m * N + n] = acc[i][j][q] + bv;
      }
    }
  }
}

// merged qkv + pos GEMM: blocks 0..767 -> qkv [4096,3072]; 768..831 -> pos
__global__ __launch_bounds__(256) void gemm_qkvpos_kernel(
    const ushort* __restrict__ ibf, const ushort* __restrict__ Wi,
    const float* __restrict__ in_b, ushort* __restrict__ qkvb,
    const ushort* __restrict__ pbf, const ushort* __restrict__ Wp,
    const float* __restrict__ pos_b, ushort* __restrict__ rbufb) {
  __shared__ __align__(16) ushort As[128 * 32];
  __shared__ __align__(16) ushort Bs[128 * 32];
  int f = blockIdx.x;
  if (f < 768) {
    gemm_body<true>(ibf, Wi, in_b, qkvb, E3, E_DIM,
                    (f / 24) * 128, (f % 24) * 128, As, Bs);
  } else {
    int f2 = f - 768;
    gemm_body<true>(pbf, Wp, pos_b, rbufb, E_DIM, E_DIM,
                    (f2 / 8) * 128, (f2 % 8) * 128, As, Bs);
  }
}

// out-proj GEMM (f32 out)
__global__ __launch_bounds__(256) void gemm_out_kernel(
    const ushort* __restrict__ A, const ushort* __restrict__ B,
    const float* __restrict__ bias, float* __restrict__ C,
    int M, int N, int K) {
  __shared__ __align__(16) ushort As[128 * 32];
  __shared__ __align__(16) ushort Bs[128 * 32];
  gemm_body<false>(A, B, bias, C, N, K,
                   blockIdx.y * 128, blockIdx.x * 128, As, Bs);
}

// ---------------- MFMA rel-shift attention v13 -------------------------------
// attn12 + double-buffered X region (T3 phase restructure):
//   tile ti (p=ti&1): {stage K/R(ti+1)->X[q]  ||  AC+W MFMA on X[p]} -> b1 ->
//   {scores; P/V -> X[p]} -> b2 -> {PV on X[p]} -> b3.
// 3 barriers/tile (was 4) and staging ds_writes overlap the MFMA phase.
// Hazard ledger (each pair separated by >=1 barrier):
//   stage->X[q] vs PV-read(ti-1,X[q]): b3(ti-1).  ACW-read(X[p]) vs P/V-write
//   (X[p]): b1.  P/V-write vs PV-read: b2.  PV-read vs stage(ti+1,X[p]): b3.
//   Wb ring write(ACW ti) vs score-read(ti): b1; vs score-read(ti-1): b2+b3
//   of ti-1. Q4 frags hoisted to registers (loop-invariant).
static __device__ __forceinline__ int kri(int row, int d) {
  return (row * 72 + d) ^ ((row & 8) ? 8 : 0);
}
static __device__ __forceinline__ int vdi(int d, int s) {
  return 64 * 72 + ((d * 72 + s) ^ (((d >> 3) & 7) << 3));
}

__global__ __launch_bounds__(256) void attn13_kernel(
    const ushort* __restrict__ qkv, const ushort* __restrict__ rb,
    const float* __restrict__ rwb, const float* __restrict__ rrb,
    ushort* __restrict__ outb) {
  __shared__ __align__(16) ushort Xls2[2][128 * 72];  // double-buffered region
  __shared__ __align__(16) ushort Q4ls[16 * 72];      // qr row 64 (prologue)
  __shared__ __align__(16) ushort Wb[65 * 136];       // W[t'][ring col 0..130]

  // T1: XCD swizzle. flat in dispatch order (x fastest); n=1024, 8 XCDs.
  const int flat = blockIdx.y * 16 + blockIdx.x;
  const int swz = (flat & 7) * 128 + (flat >> 3);
  const int t0 = (swz & 15) * 64;
  const int byy = swz >> 4;
  const int b = byy >> 4, h = byy & 15;

  const int tid = threadIdx.x;
  const int l = tid & 63, w = tid >> 6;
  const int fr = l & 15, fq = l >> 4;
  const int srow = tid >> 2;        // 0..63
  const int sd0 = (tid & 3) * 16;   // 0,16,32,48

  ushort* X0 = Xls2[0];
  ushort* X1 = Xls2[1];

  // async K/R tile loads (registers)
  u16x8 kr0, kr1, rr0, rr1;
  auto loadK = [&](int ti) {
    long long ko =
        ((long long)(ti * 64 + srow) * B_SZ + b) * E3 + E_DIM + h * 64 + sd0;
    kr0 = *(const u16x8*)(qkv + ko);
    kr1 = *(const u16x8*)(qkv + ko + 8);
  };
  auto loadR = [&](int ti) {
    int g = 1024 + 64 * ti - t0 + srow;
    int cr = (g <= 1023) ? g : g - 1025;
#pragma unroll
    for (int j = 0; j < 8; ++j) { rr0[j] = 0; rr1[j] = 0; }
    if (cr >= 0 && cr < 1024) {
      long long ro = (long long)cr * E_DIM + h * 64 + sd0;
      rr0 = *(const u16x8*)(rb + ro);
      rr1 = *(const u16x8*)(rb + ro + 8);
    }
  };
  loadK(0);
  loadR(0);  // issue ASAP; consumed at prologue staging

  // ---- prologue A: q+rwb -> X0 rows 0..63; hoist qw B-frags ----
  {
    long long qo = ((long long)(t0 + srow) * B_SZ + b) * E3 + h * 64 + sd0;
#pragma unroll
    for (int j = 0; j < 16; ++j)
      X0[kri(srow, sd0 + j)] =
          f2bf(bf2f(qkv[qo + j]) + rwb[h * 64 + sd0 + j]);
  }
  __syncthreads();
  const bf16x8 bQw0 = *(const bf16x8*)(X0 + kri(16 * w + fr, fq * 8));
  const bf16x8 bQw1 = *(const bf16x8*)(X0 + kri(16 * w + fr, fq * 8 + 32));
  __syncthreads();
  // ---- prologue B: q+rrb -> X0 rows 0..63, row 64 -> Q4ls;
  //      prologue C: ring cols 0..63 (g=960-t0+srow) -> X1 rows 64..127 ----
  {
    long long qo = ((long long)(t0 + srow) * B_SZ + b) * E3 + h * 64 + sd0;
#pragma unroll
    for (int j = 0; j < 16; ++j)
      X0[kri(srow, sd0 + j)] =
          f2bf(bf2f(qkv[qo + j]) + rrb[h * 64 + sd0 + j]);
  }
  if (tid < 64) {
    int row = tid >> 2;
    int d0 = (tid & 3) * 16;
    if (row == 0 && t0 + 64 < T_SEQ) {
      long long qo = ((long long)(t0 + 64) * B_SZ + b) * E3 + h * 64 + d0;
#pragma unroll
      for (int j = 0; j < 16; ++j)
        Q4ls[kri(row, d0 + j)] =
            f2bf(bf2f(qkv[qo + j]) + rrb[h * 64 + d0 + j]);
    } else {
#pragma unroll
      for (int j = 0; j < 16; ++j) Q4ls[kri(row, d0 + j)] = 0;
    }
  }
  {
    int g = 960 - t0 + srow;  // <= 1023 always
    u16x8 r0, r1;
#pragma unroll
    for (int j = 0; j < 8; ++j) { r0[j] = 0; r1[j] = 0; }
    if (g >= 0) {
      long long ro = (long long)g * E_DIM + h * 64 + sd0;
      r0 = *(const u16x8*)(rb + ro);
      r1 = *(const u16x8*)(rb + ro + 8);
    }
    *(u16x8*)(X1 + kri(64 + srow, sd0)) = r0;
    *(u16x8*)(X1 + kri(64 + srow, sd0 + 8)) = r1;
  }
  __syncthreads();
  bf16x8 bQr0[4], bQr1[4];
#pragma unroll
  for (int j = 0; j < 4; ++j) {
    bQr0[j] = *(const bf16x8*)(X0 + kri(16 * j + fr, fq * 8));
    bQr1[j] = *(const bf16x8*)(X0 + kri(16 * j + fr, fq * 8 + 32));
  }
  const bf16x8 bQ40 = *(const bf16x8*)(Q4ls + kri(fr, fq * 8));
  const bf16x8 bQ41 = *(const bf16x8*)(Q4ls + kri(fr, fq * 8 + 32));
  __syncthreads();  // hoist reads done before K(0) overwrites X0

  // W-phase (swapped): wave w computes its 16 new cols x all t' 0..64;
  // reads R window from Xbuf rows 64..127. Ring cols 0..3 mirrored to 128+.
  auto wphase = [&](int rbase, const ushort* Xbuf) {
    bf16x8 a0 = *(const bf16x8*)(Xbuf + kri(64 + 16 * w + fr, fq * 8));
    bf16x8 a1 = *(const bf16x8*)(Xbuf + kri(64 + 16 * w + fr, fq * 8 + 32));
    const int cb = (rbase & 64) + 16 * w + 4 * fq;  // ring col base (+q)
#pragma unroll
    for (int j = 0; j < 4; ++j) {
      f32x4 acw;
#pragma unroll
      for (int q = 0; q < 4; ++q) acw[q] = 0.f;
      acw = __builtin_amdgcn_mfma_f32_16x16x32_bf16(a0, bQr0[j], acw, 0, 0, 0);
      acw = __builtin_amdgcn_mfma_f32_16x16x32_bf16(a1, bQr1[j], acw, 0, 0, 0);
      ushort4 pk;
      pk.x = f2bf(acw[0]); pk.y = f2bf(acw[1]);
      pk.z = f2bf(acw[2]); pk.w = f2bf(acw[3]);
      *(ushort4*)(Wb + (16 * j + fr) * 136 + cb) = pk;
      if (cb == 0)
        *(ushort4*)(Wb + (16 * j + fr) * 136 + 128) = pk;
    }
    {
      f32x4 acw;
#pragma unroll
      for (int q = 0; q < 4; ++q) acw[q] = 0.f;
      acw = __builtin_amdgcn_mfma_f32_16x16x32_bf16(a0, bQ40, acw, 0, 0, 0);
      acw = __builtin_amdgcn_mfma_f32_16x16x32_bf16(a1, bQ41, acw, 0, 0, 0);
      if (fr == 0) {
        ushort4 pk;
        pk.x = f2bf(acw[0]); pk.y = f2bf(acw[1]);
        pk.z = f2bf(acw[2]); pk.w = f2bf(acw[3]);
        *(ushort4*)(Wb + 64 * 136 + cb) = pk;
        if (cb == 0) *(ushort4*)(Wb + 64 * 136 + 128) = pk;
      }
    }
  };

  // ---- prologue finish: wphase(0) from X1; stage K(0)/R(0) -> X0; prefetch(1)
  wphase(0, X1);
  *(u16x8*)(X0 + kri(srow, sd0)) = kr0;
  *(u16x8*)(X0 + kri(srow, sd0 + 8)) = kr1;
  *(u16x8*)(X0 + kri(64 + srow, sd0)) = rr0;
  *(u16x8*)(X0 + kri(64 + srow, sd0 + 8)) = rr1;
  loadK(1);
  loadR(1);
  barrier_lgkm();

  float m_s = -1e30f, l_s = 0.f;
  f32x4 oacc[4];
#pragma unroll
  for (int c = 0; c < 4; ++c)
#pragma unroll
    for (int q = 0; q < 4; ++q) oacc[c][q] = 0.f;

  const int dt_ = 16 * w + fr;  // this lane's t-row (softmax space)
  const int diag = t0 >> 6;
  const ushort* rowp = Wb + dt_ * 136;
  int cb4[4];
#pragma unroll
  for (int i = 0; i < 4; ++i)
    cb4[i] = (63 + 16 * i + 4 * fq - dt_) & 127;

  for (int ti = 0; ti < 16; ++ti) {
    const int s0 = ti * 64;
    const int p = ti & 1;
    ushort* Xp = Xls2[p];
    ushort* Xq = Xls2[p ^ 1];
    // phase a (overlaps ACW): stage K/R(ti+1) -> Xq; prefetch (ti+2); V load
    if (ti < 15) {
      *(u16x8*)(Xq + kri(srow, sd0)) = kr0;
      *(u16x8*)(Xq + kri(srow, sd0 + 8)) = kr1;
      *(u16x8*)(Xq + kri(64 + srow, sd0)) = rr0;
      *(u16x8*)(Xq + kri(64 + srow, sd0 + 8)) = rr1;
    }
    if (ti < 14) {
      loadK(ti + 2);
      loadR(ti + 2);
    }
    u16x8 v0, v1;
    {
      long long vo =
          ((long long)(s0 + srow) * B_SZ + b) * E3 + 2 * E_DIM + h * 64 + sd0;
      v0 = *(const u16x8*)(qkv + vo);
      v1 = *(const u16x8*)(qkv + vo + 8);
    }

    // phase b: AC GEMM (Xp rows 0..63) + wphase (Xp rows 64..127)
    __builtin_amdgcn_s_setprio(1);
    f32x4 accS[4];
#pragma unroll
    for (int c = 0; c < 4; ++c)
#pragma unroll
      for (int q = 0; q < 4; ++q) accS[c][q] = 0.f;
#pragma unroll
    for (int i = 0; i < 4; ++i) {
      bf16x8 a0 = *(const bf16x8*)(Xp + kri(16 * i + fr, fq * 8));
      bf16x8 a1 = *(const bf16x8*)(Xp + kri(16 * i + fr, fq * 8 + 32));
      accS[i] = __builtin_amdgcn_mfma_f32_16x16x32_bf16(a0, bQw0, accS[i], 0, 0, 0);
      accS[i] = __builtin_amdgcn_mfma_f32_16x16x32_bf16(a1, bQw1, accS[i], 0, 0, 0);
    }
    wphase(64 * (ti + 1), Xp);
    __builtin_amdgcn_s_setprio(0);
    barrier_lgkm();  // b1

    // scores + online softmax (lane owns one t-row; s spans i,fq,q)
    float pmax = -1e30f;
    if (ti != diag) {
#pragma unroll
      for (int i = 0; i < 4; ++i) {
        const ushort* rp = rowp + cb4[i];
#pragma unroll
        for (int q = 0; q < 4; ++q) {
          float sc = (accS[i][q] + bf2f(rp[q])) * 0.125f;
          accS[i][q] = sc;
          pmax = fmaxf(pmax, sc);
        }
      }
    } else {
      const int thr = t0 - s0;
      const int cadd = 64 * ti + 63;
#pragma unroll
      for (int i = 0; i < 4; ++i) {
#pragma unroll
        for (int q = 0; q < 4; ++q) {
          const int delta = 16 * i + 4 * fq + q - dt_;
          const int sel = (delta > thr) ? 1 : 0;
          const int c = (cadd + delta) & 127;
          float Wv = (delta == thr + 1) ? 0.f : bf2f(Wb[(dt_ + sel) * 136 + c]);
          float sc = (accS[i][q] + Wv) * 0.125f;
          accS[i][q] = sc;
          pmax = fmaxf(pmax, sc);
        }
      }
    }
#pragma unroll
    for (int i = 0; i < 4; ++i) cb4[i] ^= 64;
    if (ti == diag) rowp += 136;

    pmax = fmaxf(pmax, __shfl_xor(pmax, 16));
    pmax = fmaxf(pmax, __shfl_xor(pmax, 32));
    float mnew = fmaxf(m_s, pmax);
    float alpha = __expf(m_s - mnew);
    m_s = mnew;
    float ps = 0.f;
#pragma unroll
    for (int i = 0; i < 4; ++i) {
      ushort4 pk;
      float p0 = __expf(accS[i][0] - mnew);
      float p1 = __expf(accS[i][1] - mnew);
      float p2 = __expf(accS[i][2] - mnew);
      float p3 = __expf(accS[i][3] - mnew);
      ps += p0 + p1 + p2 + p3;
      pk.x = f2bf(p0); pk.y = f2bf(p1); pk.z = f2bf(p2); pk.w = f2bf(p3);
      *(ushort4*)(Xp + kri(dt_, 16 * i + 4 * fq)) = pk;  // P over dead K
    }
    ps += __shfl_xor(ps, 16);
    ps += __shfl_xor(ps, 32);
    l_s = l_s * alpha + ps;
    float av[4];
#pragma unroll
    for (int q = 0; q < 4; ++q) av[q] = __shfl(alpha, 4 * fq + q);
#pragma unroll
    for (int cfd = 0; cfd < 4; ++cfd)
#pragma unroll
      for (int q = 0; q < 4; ++q) oacc[cfd][q] *= av[q];
    // V^T [d][s] -> Xp rows 64..127 (over dead R)
#pragma unroll
    for (int j = 0; j < 8; ++j) {
      Xp[vdi(sd0 + j, srow)] = (ushort)v0[j];
      Xp[vdi(sd0 + 8 + j, srow)] = (ushort)v1[j];
    }
    barrier_lgkm();  // b2

    // PV GEMM: O[t=16w+4fq+q][d=16cfd+fr]
    __builtin_amdgcn_s_setprio(1);
#pragma unroll
    for (int ks = 0; ks < 2; ++ks) {
      bf16x8 aP = *(const bf16x8*)(Xp + kri(16 * w + fr, fq * 8 + 32 * ks));
#pragma unroll
      for (int cfd = 0; cfd < 4; ++cfd) {
        bf16x8 bV = *(const bf16x8*)(Xp + vdi(16 * cfd + fr, fq * 8 + 32 * ks));
        oacc[cfd] =
            __builtin_amdgcn_mfma_f32_16x16x32_bf16(aP, bV, oacc[cfd], 0, 0, 0);
      }
    }
    __builtin_amdgcn_s_setprio(0);
    barrier_lgkm();  // b3: PV reads done before next tile stages into Xp
  }

  // epilogue: l broadcast into PV space, write out
  float linv[4];
#pragma unroll
  for (int q = 0; q < 4; ++q) linv[q] = 1.f / __shfl(l_s, 4 * fq + q);
#pragma unroll
  for (int q = 0; q < 4; ++q) {
    int t = t0 + 16 * w + 4 * fq + q;
#pragma unroll
    for (int cfd = 0; cfd < 4; ++cfd)
      outb[((long long)t * B_SZ + b) * E_DIM + h * 64 + 16 * cfd + fr] =
          f2bf(oacc[cfd][q] * linv[q]);
  }
}

// ---------------- launch ----------------
extern "C" void kernel_launch(void* const* d_in, const int* in_sizes, int n_in,
                              void* d_out, int out_size, void* d_ws,
                              size_t ws_size, hipStream_t stream) {
  const float* input = (const float*)d_in[0];
  const float* pos   = (const float*)d_in[1];
  const int*   idx   = (const int*)d_in[2];
  const float* in_w  = (const float*)d_in[3];
  const float* in_b  = (const float*)d_in[4];
  const float* out_w = (const float*)d_in[5];
  const float* out_b = (const float*)d_in[6];
  const float* pos_w = (const float*)d_in[7];
  const float* pos_b = (const float*)d_in[8];
  const float* r_i   = (const float*)d_in[9];
  const float* s_i   = (const float*)d_in[10];
  const float* r_p   = (const float*)d_in[11];
  const float* s_p   = (const float*)d_in[12];
  const float* r_o   = (const float*)d_in[13];
  const float* s_o   = (const float*)d_in[14];
  const float* rm_i  = (const float*)d_in[15];
  const float* sm_i  = (const float*)d_in[16];
  const float* rm_p  = (const float*)d_in[17];
  const float* sm_p  = (const float*)d_in[18];
  const float* rm_o  = (const float*)d_in[19];
  const float* sm_o  = (const float*)d_in[20];
  const float* rwb   = (const float*)d_in[21];
  const float* rrb   = (const float*)d_in[22];
  float* out = (float*)d_out;

  // workspace layout (bytes), ~46 MB total
  char* base = (char*)d_ws;
  ushort* qkvb  = (ushort*)(base);                        // 24MB bf16 [4096][3072]
  ushort* rbufb = (ushort*)(base + 24ll * 1024 * 1024);   //  2MB bf16 [1024][1024]
  ushort* Wi    = (ushort*)(base + 26ll * 1024 * 1024);   //  6MB
  ushort* Wp    = (ushort*)(base + 32ll * 1024 * 1024);   //  2MB
  ushort* Wo    = (ushort*)(base + 34ll * 1024 * 1024);   //  2MB
  ushort* ibf   = (ushort*)(base + 36ll * 1024 * 1024);   //  8MB bf16 [4096][1024]
  ushort* pbf   = (ushort*)(base + 44ll * 1024 * 1024);   //  2MB
  ushort* abf   = ibf;  // attn out aliases ibf (dead after qkv GEMM)

  // 1) fused prep: casts + 3 factorizations
  prep_kernel<<<7680, 256, 0, stream>>>(
      input, pos, in_w, pos_w, out_w,
      rm_i, sm_i, r_i, s_i, rm_p, sm_p, r_p, s_p, rm_o, sm_o, r_o, s_o,
      idx, ibf, pbf, Wi, Wp, Wo);
  // 2) merged qkv + pos GEMM (768 + 64 blocks)
  gemm_qkvpos_kernel<<<832, 256, 0, stream>>>(
      ibf, Wi, in_b, qkvb, pbf, Wp, pos_b, rbufb);
  // 3) fused MFMA attention -> abf (bf16), XCD-swizzled
  attn13_kernel<<<dim3(16, 64), 256, 0, stream>>>(
      qkvb, rbufb, rwb, rrb, abf);
  // 4) out (f32) = attn @ Wo^T + bias
  gemm_out_kernel<<<dim3(E_DIM / 128, (T_SEQ * B_SZ) / 128), 256, 0, stream>>>(
      abf, Wo, out_b, out, T_SEQ * B_SZ, E_DIM, E_DIM);
}

// Round 16
// 175.593 us; speedup vs baseline: 1.3824x; 1.3824x over previous
//
#include <hip/hip_runtime.h>
#include <hip/hip_bf16.h>
#include <math.h>

#define E_DIM  1024
#define H_DIM  16
#define D_DIM  64
#define T_SEQ  1024
#define B_SZ   4
#define E3     3072
#define R_RANK 4

typedef __attribute__((ext_vector_type(8))) short bf16x8;
typedef __attribute__((ext_vector_type(8))) unsigned short u16x8;
typedef __attribute__((ext_vector_type(4))) float f32x4;

static __device__ __forceinline__ ushort f2bf(float x) {
  __hip_bfloat16 h = __float2bfloat16(x);
  return *(ushort*)&h;
}
static __device__ __forceinline__ float bf2f(ushort u) {
  unsigned int v = ((unsigned int)u) << 16;
  float f;
  __builtin_memcpy(&f, &v, 4);
  return f;
}

#define GLOAD_LDS16(g, l)                                                     \
  __builtin_amdgcn_global_load_lds(                                           \
      (const __attribute__((address_space(1))) void*)(g),                     \
      (__attribute__((address_space(3))) void*)(l), 16, 0, 0)

// ---------------- fused prep: casts + 3 factorizations, one launch ----------
static __device__ __forceinline__ void fact4(
    const float* __restrict__ W, const float* __restrict__ rm,
    const float* __restrict__ sm, const float* __restrict__ r,
    const float* __restrict__ s, ushort* __restrict__ out,
    int A, int idx, long long t) {
  long long i4 = t * 4;
  int a = (int)(i4 >> 10);        // Bc = 1024 for all three
  int bcol = (int)(i4 & 1023);
  float4 wv = *(const float4*)(W + i4);
  float ra = rm[(long long)idx * A + a];
  float4 sv = *(const float4*)(sm + (long long)idx * 1024 + bcol);
  float4 acc;
  acc.x = wv.x * ra * sv.x; acc.y = wv.y * ra * sv.y;
  acc.z = wv.z * ra * sv.z; acc.w = wv.w * ra * sv.w;
#pragma unroll
  for (int k = 0; k < R_RANK; ++k) {
    float rk = r[((long long)idx * R_RANK + k) * A + a];
    float4 sk = *(const float4*)(s + ((long long)idx * R_RANK + k) * 1024 + bcol);
    acc.x += rk * sk.x; acc.y += rk * sk.y;
    acc.z += rk * sk.z; acc.w += rk * sk.w;
  }
  ushort4 o;
  o.x = f2bf(acc.x); o.y = f2bf(acc.y); o.z = f2bf(acc.z); o.w = f2bf(acc.w);
  *(ushort4*)(out + i4) = o;
}

__global__ __launch_bounds__(256) void prep_kernel(
    const float* __restrict__ input, const float* __restrict__ pos,
    const float* __restrict__ in_w, const float* __restrict__ pos_w,
    const float* __restrict__ out_w,
    const float* __restrict__ rm_i, const float* __restrict__ sm_i,
    const float* __restrict__ r_i, const float* __restrict__ s_i,
    const float* __restrict__ rm_p, const float* __restrict__ sm_p,
    const float* __restrict__ r_p, const float* __restrict__ s_p,
    const float* __restrict__ rm_o, const float* __restrict__ sm_o,
    const float* __restrict__ r_o, const float* __restrict__ s_o,
    const int* __restrict__ idxp,
    ushort* __restrict__ ibf, ushort* __restrict__ pbf,
    ushort* __restrict__ Wi, ushort* __restrict__ Wp,
    ushort* __restrict__ Wo) {
  const int idx = idxp[0];
  long long t = (long long)blockIdx.x * blockDim.x + threadIdx.x;
  if (t < 524288) {  // cast input: 8 f32 -> 8 bf16
    float4 v0 = *(const float4*)(input + t * 8);
    float4 v1 = *(const float4*)(input + t * 8 + 4);
    ushort4 o0, o1;
    o0.x = f2bf(v0.x); o0.y = f2bf(v0.y); o0.z = f2bf(v0.z); o0.w = f2bf(v0.w);
    o1.x = f2bf(v1.x); o1.y = f2bf(v1.y); o1.z = f2bf(v1.z); o1.w = f2bf(v1.w);
    *(ushort4*)(ibf + t * 8) = o0;
    *(ushort4*)(ibf + t * 8 + 4) = o1;
    return;
  }
  t -= 524288;
  if (t < 131072) {  // cast pos
    float4 v0 = *(const float4*)(pos + t * 8);
    float4 v1 = *(const float4*)(pos + t * 8 + 4);
    ushort4 o0, o1;
    o0.x = f2bf(v0.x); o0.y = f2bf(v0.y); o0.z = f2bf(v0.z); o0.w = f2bf(v0.w);
    o1.x = f2bf(v1.x); o1.y = f2bf(v1.y); o1.z = f2bf(v1.z); o1.w = f2bf(v1.w);
    *(ushort4*)(pbf + t * 8) = o0;
    *(ushort4*)(pbf + t * 8 + 4) = o1;
    return;
  }
  t -= 131072;
  if (t < 786432) { fact4(in_w, rm_i, sm_i, r_i, s_i, Wi, E3, idx, t); return; }
  t -= 786432;
  if (t < 262144) { fact4(pos_w, rm_p, sm_p, r_p, s_p, Wp, E_DIM, idx, t); return; }
  t -= 262144;
  fact4(out_w, rm_o, sm_o, r_o, s_o, Wo, E_DIM, idx, t);
}

// ---------------- bf16 MFMA GEMM body (m97-style, BK=32) --------------------
template <bool BF16OUT>
static __device__ __forceinline__ void gemm_body(
    const ushort* __restrict__ A, const ushort* __restrict__ B,
    const float* __restrict__ bias, void* __restrict__ Cv,
    int N, int K, int m0, int n0, ushort* As, ushort* Bs) {
  const int tid = threadIdx.x;
  const int l = tid & 63, w = tid >> 6;
  const int mw = (w >> 1) * 64, nw = (w & 1) * 64;
  const int fr = l & 15, fq = l >> 4;
  const int lrow = l >> 2;
  const int lk = (l & 3) * 8;

  f32x4 acc[4][4];
#pragma unroll
  for (int i = 0; i < 4; ++i)
#pragma unroll
    for (int j = 0; j < 4; ++j)
#pragma unroll
      for (int q = 0; q < 4; ++q) acc[i][j][q] = 0.f;

  for (int k0 = 0; k0 < K; k0 += 32) {
    __syncthreads();
#pragma unroll
    for (int p = 0; p < 2; ++p) {
      int row = w * 32 + p * 16;
      GLOAD_LDS16(A + (long long)(m0 + row + lrow) * K + k0 + lk,
                  As + row * 32);
      GLOAD_LDS16(B + (long long)(n0 + row + lrow) * K + k0 + lk,
                  Bs + row * 32);
    }
    __syncthreads();
    bf16x8 af[4], bfr[4];
#pragma unroll
    for (int i = 0; i < 4; ++i) {
      af[i]  = *(const bf16x8*)(As + (mw + i * 16 + fr) * 32 + fq * 8);
      bfr[i] = *(const bf16x8*)(Bs + (nw + i * 16 + fr) * 32 + fq * 8);
    }
#pragma unroll
    for (int i = 0; i < 4; ++i)
#pragma unroll
      for (int j = 0; j < 4; ++j)
        acc[i][j] = __builtin_amdgcn_mfma_f32_16x16x32_bf16(
            af[i], bfr[j], acc[i][j], 0, 0, 0);
  }
#pragma unroll
  for (int i = 0; i < 4; ++i) {
#pragma unroll
    for (int j = 0; j < 4; ++j) {
      int n = n0 + nw + j * 16 + fr;
      float bv = bias[n];
#pragma unroll
      for (int q = 0; q < 4; ++q) {
        int m = m0 + mw + i * 16 + fq * 4 + q;
        if constexpr (BF16OUT)
          ((ushort*)Cv)[(long long)m * N + n] = f2bf(acc[i][j][q] + bv);
        else
          ((float*)Cv)[(long long)m * N + n] = acc[i][j][q] + bv;
      }
    }
  }
}

// merged qkv + pos GEMM: blocks 0..767 -> qkv [4096,3072]; 768..831 -> pos
__global__ __launch_bounds__(256) void gemm_qkvpos_kernel(
    const ushort* __restrict__ ibf, const ushort* __restrict__ Wi,
    const float* __restrict__ in_b, ushort* __restrict__ qkvb,
    const ushort* __restrict__ pbf, const ushort* __restrict__ Wp,
    const float* __restrict__ pos_b, ushort* __restrict__ rbufb) {
  __shared__ __align__(16) ushort As[128 * 32];
  __shared__ __align__(16) ushort Bs[128 * 32];
  int f = blockIdx.x;
  if (f < 768) {
    gemm_body<true>(ibf, Wi, in_b, qkvb, E3, E_DIM,
                    (f / 24) * 128, (f % 24) * 128, As, Bs);
  } else {
    int f2 = f - 768;
    gemm_body<true>(pbf, Wp, pos_b, rbufb, E_DIM, E_DIM,
                    (f2 / 8) * 128, (f2 % 8) * 128, As, Bs);
  }
}

// out-proj GEMM (f32 out)
__global__ __launch_bounds__(256) void gemm_out_kernel(
    const ushort* __restrict__ A, const ushort* __restrict__ B,
    const float* __restrict__ bias, float* __restrict__ C,
    int M, int N, int K) {
  __shared__ __align__(16) ushort As[128 * 32];
  __shared__ __align__(16) ushort Bs[128 * 32];
  gemm_body<false>(A, B, bias, C, N, K,
                   blockIdx.y * 128, blockIdx.x * 128, As, Bs);
}

// ---------------- MFMA rel-shift attention v14 -------------------------------
// Revert to the verified attn11 structure (R13, best), plus two DS-issue cuts:
//  - fast-path score reads: 16 scalar ds_read_u16 -> 8 ds_read_b64 (aligned
//    16B window per i) + cndmask/alignbit extraction (bf16->f32 via bit-ops).
//  - Q4 B-frags hoisted to registers (Q4ls never overwritten; -2 b128/tile).
static __device__ __forceinline__ int kri(int row, int d) {
  return (row * 72 + d) ^ ((row & 8) ? 8 : 0);
}
static __device__ __forceinline__ int vdi(int d, int s) {
  return 64 * 72 + ((d * 72 + s) ^ (((d >> 3) & 7) << 3));
}

__global__ __launch_bounds__(256) void attn14_kernel(
    const ushort* __restrict__ qkv, const ushort* __restrict__ rb,
    const float* __restrict__ rwb, const float* __restrict__ rrb,
    ushort* __restrict__ outb) {
  __shared__ __align__(16) ushort Xls[128 * 72];   // dual-phase region
  __shared__ __align__(16) ushort Q4ls[16 * 72];   // qr row 64 (row 0 real)
  __shared__ __align__(16) ushort Wb[65 * 136];    // W[t'][ring col 0..130]

  // T1: XCD swizzle. flat in dispatch order (x fastest); n=1024, 8 XCDs.
  const int flat = blockIdx.y * 16 + blockIdx.x;
  const int swz = (flat & 7) * 128 + (flat >> 3);
  const int t0 = (swz & 15) * 64;
  const int byy = swz >> 4;
  const int b = byy >> 4, h = byy & 15;

  const int tid = threadIdx.x;
  const int l = tid & 63, w = tid >> 6;
  const int fr = l & 15, fq = l >> 4;
  const int srow = tid >> 2;        // 0..63
  const int sd0 = (tid & 3) * 16;   // 0,16,32,48

  // ---- prologue A: q+rwb -> Xls rows 0..63; hoist qw B-frags ----
  {
    long long qo = ((long long)(t0 + srow) * B_SZ + b) * E3 + h * 64 + sd0;
#pragma unroll
    for (int j = 0; j < 16; ++j)
      Xls[kri(srow, sd0 + j)] =
          f2bf(bf2f(qkv[qo + j]) + rwb[h * 64 + sd0 + j]);
  }
  __syncthreads();
  const bf16x8 bQw0 = *(const bf16x8*)(Xls + kri(16 * w + fr, fq * 8));
  const bf16x8 bQw1 = *(const bf16x8*)(Xls + kri(16 * w + fr, fq * 8 + 32));
  __syncthreads();
  // ---- prologue B: q+rrb rows 0..63 -> Xls, row 64 -> Q4ls ----
  {
    long long qo = ((long long)(t0 + srow) * B_SZ + b) * E3 + h * 64 + sd0;
#pragma unroll
    for (int j = 0; j < 16; ++j)
      Xls[kri(srow, sd0 + j)] =
          f2bf(bf2f(qkv[qo + j]) + rrb[h * 64 + sd0 + j]);
  }
  if (tid < 64) {
    int row = tid >> 2;
    int d0 = (tid & 3) * 16;
    if (row == 0 && t0 + 64 < T_SEQ) {
      long long qo = ((long long)(t0 + 64) * B_SZ + b) * E3 + h * 64 + d0;
#pragma unroll
      for (int j = 0; j < 16; ++j)
        Q4ls[kri(row, d0 + j)] =
            f2bf(bf2f(qkv[qo + j]) + rrb[h * 64 + d0 + j]);
    } else {
#pragma unroll
      for (int j = 0; j < 16; ++j) Q4ls[kri(row, d0 + j)] = 0;
    }
  }
  __syncthreads();
  bf16x8 bQr0[4], bQr1[4];
#pragma unroll
  for (int j = 0; j < 4; ++j) {
    bQr0[j] = *(const bf16x8*)(Xls + kri(16 * j + fr, fq * 8));
    bQr1[j] = *(const bf16x8*)(Xls + kri(16 * j + fr, fq * 8 + 32));
  }
  const bf16x8 bQ40 = *(const bf16x8*)(Q4ls + kri(fr, fq * 8));
  const bf16x8 bQ41 = *(const bf16x8*)(Q4ls + kri(fr, fq * 8 + 32));
  __syncthreads();  // hoisted reads done before ring staging overwrites

  // W-phase (swapped): wave w computes its 16 new cols x all t' 0..64.
  // Ring cols 0..3 mirrored to 128..131 for wrap-free fast reads.
  auto wphase = [&](int rbase, int rowbase) {
    bf16x8 a0 = *(const bf16x8*)(Xls + kri(rowbase + 16 * w + fr, fq * 8));
    bf16x8 a1 = *(const bf16x8*)(Xls + kri(rowbase + 16 * w + fr, fq * 8 + 32));
    const int cb = (rbase & 64) + 16 * w + 4 * fq;  // ring col base (+q)
#pragma unroll
    for (int j = 0; j < 4; ++j) {
      f32x4 acw;
#pragma unroll
      for (int q = 0; q < 4; ++q) acw[q] = 0.f;
      acw = __builtin_amdgcn_mfma_f32_16x16x32_bf16(a0, bQr0[j], acw, 0, 0, 0);
      acw = __builtin_amdgcn_mfma_f32_16x16x32_bf16(a1, bQr1[j], acw, 0, 0, 0);
      ushort4 pk;
      pk.x = f2bf(acw[0]); pk.y = f2bf(acw[1]);
      pk.z = f2bf(acw[2]); pk.w = f2bf(acw[3]);
      *(ushort4*)(Wb + (16 * j + fr) * 136 + cb) = pk;
      if (cb == 0)
        *(ushort4*)(Wb + (16 * j + fr) * 136 + 128) = pk;
    }
    {
      f32x4 acw;
#pragma unroll
      for (int q = 0; q < 4; ++q) acw[q] = 0.f;
      acw = __builtin_amdgcn_mfma_f32_16x16x32_bf16(a0, bQ40, acw, 0, 0, 0);
      acw = __builtin_amdgcn_mfma_f32_16x16x32_bf16(a1, bQ41, acw, 0, 0, 0);
      if (fr == 0) {
        ushort4 pk;
        pk.x = f2bf(acw[0]); pk.y = f2bf(acw[1]);
        pk.z = f2bf(acw[2]); pk.w = f2bf(acw[3]);
        *(ushort4*)(Wb + 64 * 136 + cb) = pk;
        if (cb == 0) *(ushort4*)(Wb + 64 * 136 + 128) = pk;
      }
    }
  };

  // async K/R tile loads (registers)
  u16x8 kr0, kr1, rr0, rr1;
  auto loadK = [&](int ti) {
    long long ko =
        ((long long)(ti * 64 + srow) * B_SZ + b) * E3 + E_DIM + h * 64 + sd0;
    kr0 = *(const u16x8*)(qkv + ko);
    kr1 = *(const u16x8*)(qkv + ko + 8);
  };
  auto loadR = [&](int ti) {
    int g = 1024 + 64 * ti - t0 + srow;
    int cr = (g <= 1023) ? g : g - 1025;
#pragma unroll
    for (int j = 0; j < 8; ++j) { rr0[j] = 0; rr1[j] = 0; }
    if (cr >= 0 && cr < 1024) {
      long long ro = (long long)cr * E_DIM + h * 64 + sd0;
      rr0 = *(const u16x8*)(rb + ro);
      rr1 = *(const u16x8*)(rb + ro + 8);
    }
  };

  // ---- prologue C: stage ring cols 0..63 into rows 64..127; compute ----
  {
    int g = 960 - t0 + srow;  // <= 1023 always
    u16x8 r0, r1;
#pragma unroll
    for (int j = 0; j < 8; ++j) { r0[j] = 0; r1[j] = 0; }
    if (g >= 0) {
      long long ro = (long long)g * E_DIM + h * 64 + sd0;
      r0 = *(const u16x8*)(rb + ro);
      r1 = *(const u16x8*)(rb + ro + 8);
    }
    *(u16x8*)(Xls + kri(64 + srow, sd0)) = r0;
    *(u16x8*)(Xls + kri(64 + srow, sd0 + 8)) = r1;
  }
  loadK(0);
  loadR(0);
  __syncthreads();
  wphase(0, 64);
  __syncthreads();

  float m_s = -1e30f, l_s = 0.f;
  f32x4 oacc[4];
#pragma unroll
  for (int c = 0; c < 4; ++c)
#pragma unroll
    for (int q = 0; q < 4; ++q) oacc[c][q] = 0.f;

  const int dt_ = 16 * w + fr;  // this lane's t-row (softmax space)
  const int diag = t0 >> 6;
  const ushort* rowp = Wb + dt_ * 136;   // row base, 272B (16B-aligned)
  int cb4[4];
#pragma unroll
  for (int i = 0; i < 4; ++i)
    cb4[i] = (63 + 16 * i + 4 * fq - dt_) & 127;

  for (int ti = 0; ti < 16; ++ti) {
    const int s0 = ti * 64;
    // write prefetched K tile -> rows 0..63 (over dead P), R -> rows 64..127
    *(u16x8*)(Xls + kri(srow, sd0)) = kr0;
    *(u16x8*)(Xls + kri(srow, sd0 + 8)) = kr1;
    *(u16x8*)(Xls + kri(64 + srow, sd0)) = rr0;
    *(u16x8*)(Xls + kri(64 + srow, sd0 + 8)) = rr1;
    if (ti < 15) {
      loadK(ti + 1);
      loadR(ti + 1);
    }
    // issue this tile's V load early (consumed after B_b)
    u16x8 v0, v1;
    {
      long long vo =
          ((long long)(s0 + srow) * B_SZ + b) * E3 + 2 * E_DIM + h * 64 + sd0;
      v0 = *(const u16x8*)(qkv + vo);
      v1 = *(const u16x8*)(qkv + vo + 8);
    }
    __syncthreads();  // B_a

    // AC GEMM (swapped): accS[i] -> S[t=16w+fr][s=16i+4fq+q]
    __builtin_amdgcn_s_setprio(1);
    f32x4 accS[4];
#pragma unroll
    for (int c = 0; c < 4; ++c)
#pragma unroll
      for (int q = 0; q < 4; ++q) accS[c][q] = 0.f;
#pragma unroll
    for (int i = 0; i < 4; ++i) {
      bf16x8 a0 = *(const bf16x8*)(Xls + kri(16 * i + fr, fq * 8));
      bf16x8 a1 = *(const bf16x8*)(Xls + kri(16 * i + fr, fq * 8 + 32));
      accS[i] = __builtin_amdgcn_mfma_f32_16x16x32_bf16(a0, bQw0, accS[i], 0, 0, 0);
      accS[i] = __builtin_amdgcn_mfma_f32_16x16x32_bf16(a1, bQw1, accS[i], 0, 0, 0);
    }
    wphase(64 * (ti + 1), 64);
    __builtin_amdgcn_s_setprio(0);
    __syncthreads();  // B_b

    // scores + online softmax (lane owns one t-row; s spans i,fq,q)
    float pmax = -1e30f;
    if (ti != diag) {
      // fast path: 2 aligned b64 reads per i-run + alignbit extraction.
      // reads stay within the 272B row: cb4<=127 -> byte window <= [248,264).
#pragma unroll
      for (int i = 0; i < 4; ++i) {
        int ob = cb4[i] * 2;            // byte offset of first ushort
        int a8 = ob & ~7;               // aligned-8 base
        uint2 lo = *(const uint2*)((const char*)rowp + a8);
        uint2 hi = *(const uint2*)((const char*)rowp + a8 + 8);
        int sb = ob & 7;                // 0,2,4,6
        unsigned e0 = (sb >= 4) ? lo.y : lo.x;
        unsigned e1 = (sb >= 4) ? hi.x : lo.y;
        unsigned e2 = (sb >= 4) ? hi.y : hi.x;
        int sh = (sb & 3) * 8;          // 0 or 16
        unsigned w0 = __builtin_amdgcn_alignbit(e1, e0, sh);
        unsigned w1 = __builtin_amdgcn_alignbit(e2, e1, sh);
        float Wv0 = __builtin_bit_cast(float, w0 << 16);
        float Wv1 = __builtin_bit_cast(float, w0 & 0xffff0000u);
        float Wv2 = __builtin_bit_cast(float, w1 << 16);
        float Wv3 = __builtin_bit_cast(float, w1 & 0xffff0000u);
        accS[i][0] = (accS[i][0] + Wv0) * 0.125f;
        accS[i][1] = (accS[i][1] + Wv1) * 0.125f;
        accS[i][2] = (accS[i][2] + Wv2) * 0.125f;
        accS[i][3] = (accS[i][3] + Wv3) * 0.125f;
        pmax = fmaxf(pmax, fmaxf(fmaxf(accS[i][0], accS[i][1]),
                                 fmaxf(accS[i][2], accS[i][3])));
      }
    } else {
      // diagonal tile: original per-element logic (mixed sel)
      const int thr = t0 - s0;
      const int cadd = 64 * ti + 63;
#pragma unroll
      for (int i = 0; i < 4; ++i) {
#pragma unroll
        for (int q = 0; q < 4; ++q) {
          const int delta = 16 * i + 4 * fq + q - dt_;
          const int sel = (delta > thr) ? 1 : 0;
          const int c = (cadd + delta) & 127;
          float Wv = (delta == thr + 1) ? 0.f : bf2f(Wb[(dt_ + sel) * 136 + c]);
          float sc = (accS[i][q] + Wv) * 0.125f;
          accS[i][q] = sc;
          pmax = fmaxf(pmax, sc);
        }
      }
    }
#pragma unroll
    for (int i = 0; i < 4; ++i) cb4[i] ^= 64;
    if (ti == diag) rowp += 136;  // sel=1 from the next tile on

    pmax = fmaxf(pmax, __shfl_xor(pmax, 16));
    pmax = fmaxf(pmax, __shfl_xor(pmax, 32));
    float mnew = fmaxf(m_s, pmax);
    float alpha = __expf(m_s - mnew);
    m_s = mnew;
    float ps = 0.f;
#pragma unroll
    for (int i = 0; i < 4; ++i) {
      ushort4 pk;
      float p0 = __expf(accS[i][0] - mnew);
      float p1 = __expf(accS[i][1] - mnew);
      float p2 = __expf(accS[i][2] - mnew);
      float p3 = __expf(accS[i][3] - mnew);
      ps += p0 + p1 + p2 + p3;
      pk.x = f2bf(p0); pk.y = f2bf(p1); pk.z = f2bf(p2); pk.w = f2bf(p3);
      *(ushort4*)(Xls + kri(dt_, 16 * i + 4 * fq)) = pk;  // P over dead K
    }
    ps += __shfl_xor(ps, 16);
    ps += __shfl_xor(ps, 32);
    l_s = l_s * alpha + ps;
    float av[4];
#pragma unroll
    for (int q = 0; q < 4; ++q) av[q] = __shfl(alpha, 4 * fq + q);
#pragma unroll
    for (int cfd = 0; cfd < 4; ++cfd)
#pragma unroll
      for (int q = 0; q < 4; ++q) oacc[cfd][q] *= av[q];
    // V^T [d][s] -> rows 64..127 (over dead R-new)
#pragma unroll
    for (int j = 0; j < 8; ++j) {
      Xls[vdi(sd0 + j, srow)] = (ushort)v0[j];
      Xls[vdi(sd0 + 8 + j, srow)] = (ushort)v1[j];
    }
    __syncthreads();  // B_c

    // PV GEMM: O[t=16w+4fq+q][d=16cfd+fr]
    __builtin_amdgcn_s_setprio(1);
#pragma unroll
    for (int ks = 0; ks < 2; ++ks) {
      bf16x8 aP = *(const bf16x8*)(Xls + kri(16 * w + fr, fq * 8 + 32 * ks));
#pragma unroll
      for (int cfd = 0; cfd < 4; ++cfd) {
        bf16x8 bV = *(const bf16x8*)(Xls + vdi(16 * cfd + fr, fq * 8 + 32 * ks));
        oacc[cfd] =
            __builtin_amdgcn_mfma_f32_16x16x32_bf16(aP, bV, oacc[cfd], 0, 0, 0);
      }
    }
    __builtin_amdgcn_s_setprio(0);
    __syncthreads();  // B_d: PV reads done before next tile's staging
  }

  // epilogue: l broadcast into PV space, write out
  float linv[4];
#pragma unroll
  for (int q = 0; q < 4; ++q) linv[q] = 1.f / __shfl(l_s, 4 * fq + q);
#pragma unroll
  for (int q = 0; q < 4; ++q) {
    int t = t0 + 16 * w + 4 * fq + q;
#pragma unroll
    for (int cfd = 0; cfd < 4; ++cfd)
      outb[((long long)t * B_SZ + b) * E_DIM + h * 64 + 16 * cfd + fr] =
          f2bf(oacc[cfd][q] * linv[q]);
  }
}

// ---------------- launch ----------------
extern "C" void kernel_launch(void* const* d_in, const int* in_sizes, int n_in,
                              void* d_out, int out_size, void* d_ws,
                              size_t ws_size, hipStream_t stream) {
  const float* input = (const float*)d_in[0];
  const float* pos   = (const float*)d_in[1];
  const int*   idx   = (const int*)d_in[2];
  const float* in_w  = (const float*)d_in[3];
  const float* in_b  = (const float*)d_in[4];
  const float* out_w = (const float*)d_in[5];
  const float* out_b = (const float*)d_in[6];
  const float* pos_w = (const float*)d_in[7];
  const float* pos_b = (const float*)d_in[8];
  const float* r_i   = (const float*)d_in[9];
  const float* s_i   = (const float*)d_in[10];
  const float* r_p   = (const float*)d_in[11];
  const float* s_p   = (const float*)d_in[12];
  const float* r_o   = (const float*)d_in[13];
  const float* s_o   = (const float*)d_in[14];
  const float* rm_i  = (const float*)d_in[15];
  const float* sm_i  = (const float*)d_in[16];
  const float* rm_p  = (const float*)d_in[17];
  const float* sm_p  = (const float*)d_in[18];
  const float* rm_o  = (const float*)d_in[19];
  const float* sm_o  = (const float*)d_in[20];
  const float* rwb   = (const float*)d_in[21];
  const float* rrb   = (const float*)d_in[22];
  float* out = (float*)d_out;

  // workspace layout (bytes), ~46 MB total
  char* base = (char*)d_ws;
  ushort* qkvb  = (ushort*)(base);                        // 24MB bf16 [4096][3072]
  ushort* rbufb = (ushort*)(base + 24ll * 1024 * 1024);   //  2MB bf16 [1024][1024]
  ushort* Wi    = (ushort*)(base + 26ll * 1024 * 1024);   //  6MB
  ushort* Wp    = (ushort*)(base + 32ll * 1024 * 1024);   //  2MB
  ushort* Wo    = (ushort*)(base + 34ll * 1024 * 1024);   //  2MB
  ushort* ibf   = (ushort*)(base + 36ll * 1024 * 1024);   //  8MB bf16 [4096][1024]
  ushort* pbf   = (ushort*)(base + 44ll * 1024 * 1024);   //  2MB
  ushort* abf   = ibf;  // attn out aliases ibf (dead after qkv GEMM)

  // 1) fused prep: casts + 3 factorizations
  prep_kernel<<<7680, 256, 0, stream>>>(
      input, pos, in_w, pos_w, out_w,
      rm_i, sm_i, r_i, s_i, rm_p, sm_p, r_p, s_p, rm_o, sm_o, r_o, s_o,
      idx, ibf, pbf, Wi, Wp, Wo);
  // 2) merged qkv + pos GEMM (768 + 64 blocks)
  gemm_qkvpos_kernel<<<832, 256, 0, stream>>>(
      ibf, Wi, in_b, qkvb, pbf, Wp, pos_b, rbufb);
  // 3) fused MFMA attention -> abf (bf16), XCD-swizzled
  attn14_kernel<<<dim3(16, 64), 256, 0, stream>>>(
      qkvb, rbufb, rwb, rrb, abf);
  // 4) out (f32) = attn @ Wo^T + bias
  gemm_out_kernel<<<dim3(E_DIM / 128, (T_SEQ * B_SZ) / 128), 256, 0, stream>>>(
      abf, Wo, out_b, out, T_SEQ * B_SZ, E_DIM, E_DIM);
}